// Round 1
// baseline (470.804 us; speedup 1.0000x reference)
//
#include <hip/hip_runtime.h>
#include <math.h>

#define NEG_SLOPE 0.2f

// ---------------- K0: v_edge[h*16+j] = sum_c W_edge[j][h*32+c] * att_edge[h][c]
__global__ void k0_vedge(const float* __restrict__ W_edge, const float* __restrict__ att_edge,
                         float* __restrict__ v_edge) {
  int t = threadIdx.x;           // 64 threads
  int h = t >> 4, j = t & 15;
  float s = 0.f;
#pragma unroll
  for (int c = 0; c < 32; ++c) s += W_edge[j * 128 + h * 32 + c] * att_edge[h * 32 + c];
  v_edge[t] = s;
}

// ---------------- detect int64 edge_index (values < 2^31 -> high dwords all zero)
__global__ void k_detect(const int* __restrict__ ei, int* __restrict__ flag) {
  __shared__ int any;
  if (threadIdx.x == 0) any = 0;
  __syncthreads();
  if (ei[2 * threadIdx.x + 1] != 0) atomicOr(&any, 1);
  __syncthreads();
  if (threadIdx.x == 0) *flag = (any == 0) ? 1 : 0;
}

__global__ void k_zero(int* __restrict__ p, int n) {
  int i = blockIdx.x * blockDim.x + threadIdx.x;
  if (i < n) p[i] = 0;
}

// ---------------- K1: x_l = x @ W  (f32, LDS-tiled), fused a_src/a_dst epilogue
// block 256, 64 rows/block, thread tile 8 rows x 4 cols, K chunked by 32.
__global__ __launch_bounds__(256) void k1_xl(
    const float* __restrict__ x, const float* __restrict__ W,
    const float* __restrict__ att_src, const float* __restrict__ att_dst,
    float* __restrict__ x_l, float* __restrict__ a_src, float* __restrict__ a_dst, int N) {
  __shared__ float Wc[32 * 128];   // 16 KB
  __shared__ float Xc[32 * 64];    // 8 KB (transposed: Xc[k][r])
  const int t = threadIdx.x;
  const int tcol = t & 31;         // cols tcol*4 .. +3   (head h = tcol>>3)
  const int trow = t >> 5;         // rows trow*8 .. +7
  const int row0 = blockIdx.x * 64;
  const int r = t & 63, kq = t >> 6;
  const float4 aw_s = *(const float4*)&att_src[tcol * 4];
  const float4 aw_d = *(const float4*)&att_dst[tcol * 4];
  float acc[8][4];
#pragma unroll
  for (int i = 0; i < 8; ++i) { acc[i][0] = acc[i][1] = acc[i][2] = acc[i][3] = 0.f; }

  for (int kc = 0; kc < 4; ++kc) {
    float4 wreg[4];
#pragma unroll
    for (int q = 0; q < 4; ++q) wreg[q] = *(const float4*)&W[kc * 4096 + (q * 256 + t) * 4];
    float xs8[8];
    int grow = row0 + r;
    if (grow < N) {
      *(float4*)&xs8[0] = *(const float4*)&x[grow * 128 + kc * 32 + kq * 8];
      *(float4*)&xs8[4] = *(const float4*)&x[grow * 128 + kc * 32 + kq * 8 + 4];
    } else {
#pragma unroll
      for (int q = 0; q < 8; ++q) xs8[q] = 0.f;
    }
    __syncthreads();   // previous chunk's compute done
#pragma unroll
    for (int q = 0; q < 4; ++q) *(float4*)&Wc[(q * 256 + t) * 4] = wreg[q];
#pragma unroll
    for (int q = 0; q < 8; ++q) Xc[(kq * 8 + q) * 64 + r] = xs8[q];
    __syncthreads();
#pragma unroll
    for (int kk = 0; kk < 32; ++kk) {
      float4 wv = *(const float4*)&Wc[kk * 128 + tcol * 4];
      float xr[8];
      *(float4*)&xr[0] = *(const float4*)&Xc[kk * 64 + trow * 8];
      *(float4*)&xr[4] = *(const float4*)&Xc[kk * 64 + trow * 8 + 4];
#pragma unroll
      for (int ri = 0; ri < 8; ++ri) {
        acc[ri][0] += xr[ri] * wv.x;
        acc[ri][1] += xr[ri] * wv.y;
        acc[ri][2] += xr[ri] * wv.z;
        acc[ri][3] += xr[ri] * wv.w;
      }
    }
  }
  // epilogue: store x_l row-slices; reduce a_src/a_dst over each head's 32 cols
#pragma unroll
  for (int ri = 0; ri < 8; ++ri) {
    int grow = row0 + trow * 8 + ri;
    float asp = acc[ri][0] * aw_s.x + acc[ri][1] * aw_s.y + acc[ri][2] * aw_s.z + acc[ri][3] * aw_s.w;
    float adp = acc[ri][0] * aw_d.x + acc[ri][1] * aw_d.y + acc[ri][2] * aw_d.z + acc[ri][3] * aw_d.w;
#pragma unroll
    for (int m = 1; m < 8; m <<= 1) { asp += __shfl_xor(asp, m); adp += __shfl_xor(adp, m); }
    if (grow < N) {
      float4 o; o.x = acc[ri][0]; o.y = acc[ri][1]; o.z = acc[ri][2]; o.w = acc[ri][3];
      *(float4*)&x_l[grow * 128 + tcol * 4] = o;
      if ((tcol & 7) == 0) {
        a_src[grow * 4 + (tcol >> 3)] = asp;
        a_dst[grow * 4 + (tcol >> 3)] = adp;
      }
    }
  }
}

// ---------------- K2a: in-degree histogram
__global__ void k_hist(const int* __restrict__ ei, const int* __restrict__ is64,
                       int* __restrict__ deg, int E) {
  int i = blockIdx.x * blockDim.x + threadIdx.x;
  if (i >= E) return;
  int dst = (*is64) ? ei[2 * (E + i)] : ei[E + i];
  atomicAdd(&deg[dst], 1);
}

// ---------------- 3-kernel exclusive scan over deg[N] (1024 elems/block)
__global__ void k_scan1(const int* __restrict__ deg, int* __restrict__ bsum, int N) {
  __shared__ int lds[256];
  int b = blockIdx.x, t = threadIdx.x;
  int base = b * 1024 + t * 4;
  int s = 0;
  if (base + 3 < N) {
    int4 v = *(const int4*)&deg[base];
    s = v.x + v.y + v.z + v.w;
  } else {
    for (int q = 0; q < 4; ++q) if (base + q < N) s += deg[base + q];
  }
  lds[t] = s; __syncthreads();
  for (int st = 128; st > 0; st >>= 1) {
    if (t < st) lds[t] += lds[t + st];
    __syncthreads();
  }
  if (t == 0) bsum[b] = lds[0];
}

__global__ void k_scan2(const int* __restrict__ bsum, int* __restrict__ boff, int NB) {
  __shared__ int lds[256];
  int t = threadIdx.x;
  int v = (t < NB) ? bsum[t] : 0;
  lds[t] = v;
  __syncthreads();
  for (int st = 1; st < 256; st <<= 1) {
    int add = (t >= st) ? lds[t - st] : 0;
    __syncthreads();
    lds[t] += add;
    __syncthreads();
  }
  if (t < NB) boff[t] = lds[t] - v;   // exclusive
}

__global__ void k_scan3(const int* __restrict__ deg, const int* __restrict__ boff,
                        int* __restrict__ offs, int* __restrict__ cursor, int N) {
  __shared__ int lds[256];
  int b = blockIdx.x, t = threadIdx.x;
  int base = b * 1024 + t * 4;
  int v[4]; int s = 0;
#pragma unroll
  for (int q = 0; q < 4; ++q) { v[q] = (base + q < N) ? deg[base + q] : 0; s += v[q]; }
  lds[t] = s;
  __syncthreads();
  for (int st = 1; st < 256; st <<= 1) {
    int add = (t >= st) ? lds[t - st] : 0;
    __syncthreads();
    lds[t] += add;
    __syncthreads();
  }
  int run = boff[b] + lds[t] - s;
#pragma unroll
  for (int q = 0; q < 4; ++q) {
    if (base + q < N) { offs[base + q] = run; cursor[base + q] = run; }
    run += v[q];
  }
}

// ---------------- K2c: counting-sort scatter (edge id + src, ordered by dst)
__global__ void k_scatter(const int* __restrict__ ei, const int* __restrict__ is64,
                          int* __restrict__ cursor, int* __restrict__ s_eid,
                          int* __restrict__ s_src, int E) {
  int i = blockIdx.x * blockDim.x + threadIdx.x;
  if (i >= E) return;
  int f = *is64;
  int src = f ? ei[2 * i] : ei[i];
  int dst = f ? ei[2 * (E + i)] : ei[E + i];
  int pos = atomicAdd(&cursor[dst], 1);
  s_eid[pos] = i;
  s_src[pos] = src;
}

// ---------------- K3: per-node softmax denominators (no max-sub; logits bounded)
// 16 lanes per node; p stored at sorted position; self-loop handled via mean(a_edge).
__global__ __launch_bounds__(256) void k3_softmax(
    const int* __restrict__ s_eid, const int* __restrict__ s_src,
    const float* __restrict__ edge_attr, const float* __restrict__ a_src,
    const float* __restrict__ a_dst, const float* __restrict__ v_edge,
    const int* __restrict__ deg, const int* __restrict__ offs,
    float* __restrict__ p_sorted, float* __restrict__ inv_den,
    float* __restrict__ aloop, int N) {
  __shared__ float ve[64];
  int t = threadIdx.x;
  if (t < 64) ve[t] = v_edge[t];
  __syncthreads();
  int node = blockIdx.x * 16 + (t >> 4);
  int sl = t & 15;
  if (node >= N) return;
  int off = offs[node], dg = deg[node];
  float ad4[4]; *(float4*)ad4 = *(const float4*)&a_dst[node * 4];
  float den[4] = {0, 0, 0, 0}, sae[4] = {0, 0, 0, 0};
  for (int i = sl; i < dg; i += 16) {
    int pos = off + i;
    int eid = s_eid[pos];
    int src = s_src[pos];
    float a16[16];
    *(float4*)&a16[0]  = *(const float4*)&edge_attr[eid * 16];
    *(float4*)&a16[4]  = *(const float4*)&edge_attr[eid * 16 + 4];
    *(float4*)&a16[8]  = *(const float4*)&edge_attr[eid * 16 + 8];
    *(float4*)&a16[12] = *(const float4*)&edge_attr[eid * 16 + 12];
    float as4[4]; *(float4*)as4 = *(const float4*)&a_src[src * 4];
    float p4[4];
#pragma unroll
    for (int h = 0; h < 4; ++h) {
      float ae = 0.f;
#pragma unroll
      for (int j = 0; j < 16; ++j) ae += a16[j] * ve[h * 16 + j];
      float lg = as4[h] + ad4[h] + ae;
      lg = (lg >= 0.f) ? lg : NEG_SLOPE * lg;
      float p = __expf(lg);
      p4[h] = p;
      den[h] += p;
      sae[h] += ae;
    }
    *(float4*)&p_sorted[pos * 4] = *(float4*)p4;
  }
#pragma unroll
  for (int m = 1; m < 16; m <<= 1) {
#pragma unroll
    for (int h = 0; h < 4; ++h) { den[h] += __shfl_xor(den[h], m); sae[h] += __shfl_xor(sae[h], m); }
  }
  if (sl == 0) {
    float as4[4]; *(float4*)as4 = *(const float4*)&a_src[node * 4];
    float inv_cnt = 1.f / (float)(dg > 0 ? dg : 1);
    float id4[4], al4[4];
#pragma unroll
    for (int h = 0; h < 4; ++h) {
      float lae = sae[h] * inv_cnt;                 // mean a_edge (linearity of fill='mean')
      float lg = as4[h] + ad4[h] + lae;
      lg = (lg >= 0.f) ? lg : NEG_SLOPE * lg;
      float pl = __expf(lg);
      float dt = den[h] + pl;
      float iv = 1.f / dt;
      id4[h] = iv; al4[h] = pl * iv;
    }
    *(float4*)&inv_den[node * 4] = *(float4*)id4;
    *(float4*)&aloop[node * 4]  = *(float4*)al4;
  }
}

// ---------------- K4: atomic-free aggregation, one wave per node, lane = column
__global__ __launch_bounds__(256) void k4_agg(
    const int* __restrict__ s_src, const float* __restrict__ p_sorted,
    const float* __restrict__ x_l, const float* __restrict__ inv_den,
    const float* __restrict__ aloop, const int* __restrict__ deg,
    const int* __restrict__ offs, const float* __restrict__ bias,
    float* __restrict__ out, int N) {
  int lane = threadIdx.x & 63;
  int node = blockIdx.x * 4 + (threadIdx.x >> 6);
  if (node >= N) return;
  int off = offs[node], dg = deg[node];
  int h0 = lane >> 5, h1 = 2 + h0;
  float iv0 = inv_den[node * 4 + h0], iv1 = inv_den[node * 4 + h1];
  float acc0 = aloop[node * 4 + h0] * x_l[node * 128 + lane];
  float acc1 = aloop[node * 4 + h1] * x_l[node * 128 + 64 + lane];
  for (int i = 0; i < dg; ++i) {
    int pos = off + i;
    int src = s_src[pos];
    float a0 = p_sorted[pos * 4 + h0] * iv0;
    float a1 = p_sorted[pos * 4 + h1] * iv1;
    acc0 += a0 * x_l[src * 128 + lane];
    acc1 += a1 * x_l[src * 128 + 64 + lane];
  }
  out[node * 128 + lane] = acc0 + bias[lane];
  out[node * 128 + 64 + lane] = acc1 + bias[64 + lane];
}

extern "C" void kernel_launch(void* const* d_in, const int* in_sizes, int n_in,
                              void* d_out, int out_size, void* d_ws, size_t ws_size,
                              hipStream_t stream) {
  const float* x        = (const float*)d_in[0];
  const int*   ei       = (const int*)  d_in[1];
  const float* eattr    = (const float*)d_in[2];
  const float* W        = (const float*)d_in[3];
  const float* W_edge   = (const float*)d_in[4];
  const float* att_src  = (const float*)d_in[5];
  const float* att_dst  = (const float*)d_in[6];
  const float* att_edge = (const float*)d_in[7];
  const float* bias     = (const float*)d_in[8];
  float* out = (float*)d_out;
  const int N = in_sizes[0] / 128;
  const int E = in_sizes[1] / 2;
  (void)n_in; (void)out_size; (void)ws_size;

  // workspace layout (~98 MB total)
  char* base = (char*)d_ws;
  size_t off = 0;
  auto take = [&](size_t bytes) -> void* {
    void* p = base + off;
    off = (off + bytes + 255) & ~(size_t)255;
    return p;
  };
  float* x_l      = (float*)take((size_t)N * 128 * 4);
  float* a_src    = (float*)take((size_t)N * 4 * 4);
  float* a_dst    = (float*)take((size_t)N * 4 * 4);
  float* v_edge   = (float*)take(64 * 4);
  float* p_sorted = (float*)take((size_t)E * 4 * 4);
  float* inv_den  = (float*)take((size_t)N * 4 * 4);
  float* aloop    = (float*)take((size_t)N * 4 * 4);
  int*   deg      = (int*)take((size_t)N * 4);
  int*   offs     = (int*)take((size_t)N * 4);
  int*   cursor   = (int*)take((size_t)N * 4);
  int*   bsum     = (int*)take(256 * 4);
  int*   boff     = (int*)take(256 * 4);
  int*   s_eid    = (int*)take((size_t)E * 4);
  int*   s_src    = (int*)take((size_t)E * 4);
  int*   is64     = (int*)take(4);

  const int NB = (N + 1023) / 1024;   // 98 for N=100000 (scan2 supports <=256)

  hipLaunchKernelGGL(k_detect, dim3(1), dim3(256), 0, stream, ei, is64);
  hipLaunchKernelGGL(k_zero, dim3((N + 255) / 256), dim3(256), 0, stream, deg, N);
  hipLaunchKernelGGL(k0_vedge, dim3(1), dim3(64), 0, stream, W_edge, att_edge, v_edge);
  hipLaunchKernelGGL(k1_xl, dim3((N + 63) / 64), dim3(256), 0, stream,
                     x, W, att_src, att_dst, x_l, a_src, a_dst, N);
  hipLaunchKernelGGL(k_hist, dim3((E + 255) / 256), dim3(256), 0, stream, ei, is64, deg, E);
  hipLaunchKernelGGL(k_scan1, dim3(NB), dim3(256), 0, stream, deg, bsum, N);
  hipLaunchKernelGGL(k_scan2, dim3(1), dim3(256), 0, stream, bsum, boff, NB);
  hipLaunchKernelGGL(k_scan3, dim3(NB), dim3(256), 0, stream, deg, boff, offs, cursor, N);
  hipLaunchKernelGGL(k_scatter, dim3((E + 255) / 256), dim3(256), 0, stream,
                     ei, is64, cursor, s_eid, s_src, E);
  hipLaunchKernelGGL(k3_softmax, dim3((N + 15) / 16), dim3(256), 0, stream,
                     s_eid, s_src, eattr, a_src, a_dst, v_edge, deg, offs,
                     p_sorted, inv_den, aloop, N);
  hipLaunchKernelGGL(k4_agg, dim3((N + 3) / 4), dim3(256), 0, stream,
                     s_src, p_sorted, x_l, inv_den, aloop, deg, offs, bias, out, N);
}

// Round 2
// 333.225 us; speedup vs baseline: 1.4129x; 1.4129x over previous
//
#include <hip/hip_runtime.h>
#include <hip/hip_fp16.h>
#include <math.h>

#define NEG_SLOPE 0.2f
typedef unsigned short ushort_t;
typedef unsigned int uint_t;

// ---------------- K0: v_edge[h*16+j] = sum_c W_edge[j][h*32+c] * att_edge[h][c]
__global__ void k0_vedge(const float* __restrict__ W_edge, const float* __restrict__ att_edge,
                         float* __restrict__ v_edge) {
  int t = threadIdx.x;           // 64 threads
  int h = t >> 4, j = t & 15;
  float s = 0.f;
#pragma unroll
  for (int c = 0; c < 32; ++c) s += W_edge[j * 128 + h * 32 + c] * att_edge[h * 32 + c];
  v_edge[t] = s;
}

// ---------------- detect int64 edge_index (values < 2^31 -> high dwords all zero)
__global__ void k_detect(const int* __restrict__ ei, int* __restrict__ flag) {
  __shared__ int any;
  if (threadIdx.x == 0) any = 0;
  __syncthreads();
  if (ei[2 * threadIdx.x + 1] != 0) atomicOr(&any, 1);
  __syncthreads();
  if (threadIdx.x == 0) *flag = (any == 0) ? 1 : 0;
}

__global__ void k_zero(int* __restrict__ p, int n) {
  int i = blockIdx.x * blockDim.x + threadIdx.x;
  if (i < n) p[i] = 0;
}

// ---------------- K1: x_l = x @ W (f32 compute), fp16 store + fused a_src/a_dst epilogue
__global__ __launch_bounds__(256) void k1_xl(
    const float* __restrict__ x, const float* __restrict__ W,
    const float* __restrict__ att_src, const float* __restrict__ att_dst,
    ushort_t* __restrict__ x_l_h, float* __restrict__ a_src, float* __restrict__ a_dst, int N) {
  __shared__ float Wc[32 * 128];   // 16 KB
  __shared__ float Xc[32 * 64];    // 8 KB (transposed: Xc[k][r])
  const int t = threadIdx.x;
  const int tcol = t & 31;         // cols tcol*4 .. +3   (head h = tcol>>3)
  const int trow = t >> 5;         // rows trow*8 .. +7
  const int row0 = blockIdx.x * 64;
  const int r = t & 63, kq = t >> 6;
  const float4 aw_s = *(const float4*)&att_src[tcol * 4];
  const float4 aw_d = *(const float4*)&att_dst[tcol * 4];
  float acc[8][4];
#pragma unroll
  for (int i = 0; i < 8; ++i) { acc[i][0] = acc[i][1] = acc[i][2] = acc[i][3] = 0.f; }

  for (int kc = 0; kc < 4; ++kc) {
    float4 wreg[4];
#pragma unroll
    for (int q = 0; q < 4; ++q) wreg[q] = *(const float4*)&W[kc * 4096 + (q * 256 + t) * 4];
    float xs8[8];
    int grow = row0 + r;
    if (grow < N) {
      *(float4*)&xs8[0] = *(const float4*)&x[grow * 128 + kc * 32 + kq * 8];
      *(float4*)&xs8[4] = *(const float4*)&x[grow * 128 + kc * 32 + kq * 8 + 4];
    } else {
#pragma unroll
      for (int q = 0; q < 8; ++q) xs8[q] = 0.f;
    }
    __syncthreads();   // previous chunk's compute done
#pragma unroll
    for (int q = 0; q < 4; ++q) *(float4*)&Wc[(q * 256 + t) * 4] = wreg[q];
#pragma unroll
    for (int q = 0; q < 8; ++q) Xc[(kq * 8 + q) * 64 + r] = xs8[q];
    __syncthreads();
#pragma unroll
    for (int kk = 0; kk < 32; ++kk) {
      float4 wv = *(const float4*)&Wc[kk * 128 + tcol * 4];
      float xr[8];
      *(float4*)&xr[0] = *(const float4*)&Xc[kk * 64 + trow * 8];
      *(float4*)&xr[4] = *(const float4*)&Xc[kk * 64 + trow * 8 + 4];
#pragma unroll
      for (int ri = 0; ri < 8; ++ri) {
        acc[ri][0] += xr[ri] * wv.x;
        acc[ri][1] += xr[ri] * wv.y;
        acc[ri][2] += xr[ri] * wv.z;
        acc[ri][3] += xr[ri] * wv.w;
      }
    }
  }
  // epilogue: fp16 store; reduce a_src/a_dst over each head's 32 cols
#pragma unroll
  for (int ri = 0; ri < 8; ++ri) {
    int grow = row0 + trow * 8 + ri;
    float asp = acc[ri][0] * aw_s.x + acc[ri][1] * aw_s.y + acc[ri][2] * aw_s.z + acc[ri][3] * aw_s.w;
    float adp = acc[ri][0] * aw_d.x + acc[ri][1] * aw_d.y + acc[ri][2] * aw_d.z + acc[ri][3] * aw_d.w;
#pragma unroll
    for (int m = 1; m < 8; m <<= 1) { asp += __shfl_xor(asp, m); adp += __shfl_xor(adp, m); }
    if (grow < N) {
      __half2 h0 = __floats2half2_rn(acc[ri][0], acc[ri][1]);
      __half2 h1 = __floats2half2_rn(acc[ri][2], acc[ri][3]);
      uint2 u; u.x = *(uint_t*)&h0; u.y = *(uint_t*)&h1;
      *(uint2*)&x_l_h[(size_t)grow * 128 + tcol * 4] = u;
      if ((tcol & 7) == 0) {
        a_src[grow * 4 + (tcol >> 3)] = asp;
        a_dst[grow * 4 + (tcol >> 3)] = adp;
      }
    }
  }
}

// ---------------- K2a: in-degree histogram
__global__ void k_hist(const int* __restrict__ ei, const int* __restrict__ is64,
                       int* __restrict__ deg, int E) {
  int i = blockIdx.x * blockDim.x + threadIdx.x;
  if (i >= E) return;
  int dst = (*is64) ? ei[2 * (E + i)] : ei[E + i];
  atomicAdd(&deg[dst], 1);
}

// ---------------- 3-kernel exclusive scan over deg[N] (1024 elems/block)
__global__ void k_scan1(const int* __restrict__ deg, int* __restrict__ bsum, int N) {
  __shared__ int lds[256];
  int b = blockIdx.x, t = threadIdx.x;
  int base = b * 1024 + t * 4;
  int s = 0;
  if (base + 3 < N) {
    int4 v = *(const int4*)&deg[base];
    s = v.x + v.y + v.z + v.w;
  } else {
    for (int q = 0; q < 4; ++q) if (base + q < N) s += deg[base + q];
  }
  lds[t] = s; __syncthreads();
  for (int st = 128; st > 0; st >>= 1) {
    if (t < st) lds[t] += lds[t + st];
    __syncthreads();
  }
  if (t == 0) bsum[b] = lds[0];
}

__global__ void k_scan2(const int* __restrict__ bsum, int* __restrict__ boff, int NB) {
  __shared__ int lds[256];
  int t = threadIdx.x;
  int v = (t < NB) ? bsum[t] : 0;
  lds[t] = v;
  __syncthreads();
  for (int st = 1; st < 256; st <<= 1) {
    int add = (t >= st) ? lds[t - st] : 0;
    __syncthreads();
    lds[t] += add;
    __syncthreads();
  }
  if (t < NB) boff[t] = lds[t] - v;   // exclusive
}

__global__ void k_scan3(const int* __restrict__ deg, const int* __restrict__ boff,
                        int* __restrict__ offs, int* __restrict__ cursor, int N) {
  __shared__ int lds[256];
  int b = blockIdx.x, t = threadIdx.x;
  int base = b * 1024 + t * 4;
  int v[4]; int s = 0;
#pragma unroll
  for (int q = 0; q < 4; ++q) { v[q] = (base + q < N) ? deg[base + q] : 0; s += v[q]; }
  lds[t] = s;
  __syncthreads();
  for (int st = 1; st < 256; st <<= 1) {
    int add = (t >= st) ? lds[t - st] : 0;
    __syncthreads();
    lds[t] += add;
    __syncthreads();
  }
  int run = boff[b] + lds[t] - s;
#pragma unroll
  for (int q = 0; q < 4; ++q) {
    if (base + q < N) { offs[base + q] = run; cursor[base + q] = run; }
    run += v[q];
  }
}

// ---------------- K2c: fused scatter — read edge_attr COALESCED, compute a_edge,
// write one 32B record {ae[4], src} per edge at its dst-sorted position.
__global__ __launch_bounds__(256) void k_scatter(
    const int* __restrict__ ei, const int* __restrict__ is64,
    const float* __restrict__ edge_attr, const float* __restrict__ v_edge,
    int* __restrict__ cursor, float* __restrict__ rec, int E) {
  __shared__ float ve[64];
  int t = threadIdx.x;
  if (t < 64) ve[t] = v_edge[t];
  __syncthreads();
  int i = blockIdx.x * 256 + t;
  if (i >= E) return;
  int f = *is64;
  int src = f ? ei[2 * i] : ei[i];
  int dst = f ? ei[2 * (E + i)] : ei[E + i];
  float a16[16];
  *(float4*)&a16[0]  = *(const float4*)&edge_attr[(size_t)i * 16];
  *(float4*)&a16[4]  = *(const float4*)&edge_attr[(size_t)i * 16 + 4];
  *(float4*)&a16[8]  = *(const float4*)&edge_attr[(size_t)i * 16 + 8];
  *(float4*)&a16[12] = *(const float4*)&edge_attr[(size_t)i * 16 + 12];
  float ae[4];
#pragma unroll
  for (int h = 0; h < 4; ++h) {
    float s = 0.f;
#pragma unroll
    for (int j = 0; j < 16; ++j) s += a16[j] * ve[h * 16 + j];
    ae[h] = s;
  }
  int pos = atomicAdd(&cursor[dst], 1);
  float4 r0; r0.x = ae[0]; r0.y = ae[1]; r0.z = ae[2]; r0.w = ae[3];
  float4 r1; r1.x = __int_as_float(src); r1.y = 0.f; r1.z = 0.f; r1.w = 0.f;
  *(float4*)&rec[(size_t)pos * 8]     = r0;
  *(float4*)&rec[(size_t)pos * 8 + 4] = r1;
}

// ---------------- K3: per-node softmax denominators; rewrites ae4 -> p4 in place.
// 16 lanes per node; all accesses coalesced (rec sequential, a_src L2-resident).
__global__ __launch_bounds__(256) void k3_softmax(
    float* __restrict__ rec, const float* __restrict__ a_src,
    const float* __restrict__ a_dst, const int* __restrict__ deg,
    const int* __restrict__ offs, float* __restrict__ inv_den,
    float* __restrict__ aloop, int N) {
  int t = threadIdx.x;
  int node = blockIdx.x * 16 + (t >> 4);
  int sl = t & 15;
  if (node >= N) return;
  int off = offs[node], dg = deg[node];
  float ad4[4]; *(float4*)ad4 = *(const float4*)&a_dst[(size_t)node * 4];
  const int* reci = (const int*)rec;
  float den[4] = {0, 0, 0, 0}, sae[4] = {0, 0, 0, 0};
  for (int i = sl; i < dg; i += 16) {
    size_t p = (size_t)(off + i) * 8;
    float aev[4]; *(float4*)aev = *(const float4*)&rec[p];
    int src = reci[p + 4];
    float as4[4]; *(float4*)as4 = *(const float4*)&a_src[(size_t)src * 4];
    float p4[4];
#pragma unroll
    for (int h = 0; h < 4; ++h) {
      float lg = as4[h] + ad4[h] + aev[h];
      lg = (lg >= 0.f) ? lg : NEG_SLOPE * lg;
      float pv = __expf(lg);
      p4[h] = pv;
      den[h] += pv;
      sae[h] += aev[h];
    }
    *(float4*)&rec[p] = *(float4*)p4;   // overwrite ae with p (in place, own slot)
  }
#pragma unroll
  for (int m = 1; m < 16; m <<= 1) {
#pragma unroll
    for (int h = 0; h < 4; ++h) { den[h] += __shfl_xor(den[h], m); sae[h] += __shfl_xor(sae[h], m); }
  }
  if (sl == 0) {
    float as4[4]; *(float4*)as4 = *(const float4*)&a_src[(size_t)node * 4];
    float inv_cnt = 1.f / (float)(dg > 0 ? dg : 1);
    float id4[4], al4[4];
#pragma unroll
    for (int h = 0; h < 4; ++h) {
      float lae = sae[h] * inv_cnt;                 // mean a_edge (linearity of fill='mean')
      float lg = as4[h] + ad4[h] + lae;
      lg = (lg >= 0.f) ? lg : NEG_SLOPE * lg;
      float pl = __expf(lg);
      float dt = den[h] + pl;
      float iv = 1.f / dt;
      id4[h] = iv; al4[h] = pl * iv;
    }
    *(float4*)&inv_den[(size_t)node * 4] = *(float4*)id4;
    *(float4*)&aloop[(size_t)node * 4]  = *(float4*)al4;
  }
}

// ---------------- K4: atomic-free aggregation, one wave per node.
// Lane covers cols {2l, 2l+1} via one half2 -> ONE 256B row load per edge.
__global__ __launch_bounds__(256) void k4_agg(
    const float* __restrict__ rec, const ushort_t* __restrict__ x_l_h,
    const float* __restrict__ inv_den, const float* __restrict__ aloop,
    const int* __restrict__ deg, const int* __restrict__ offs,
    const float* __restrict__ bias, float* __restrict__ out, int N) {
  int lane = threadIdx.x & 63;
  int node = blockIdx.x * 4 + (threadIdx.x >> 6);
  if (node >= N) return;
  int off = offs[node], dg = deg[node];
  int h = lane >> 4;                         // head of cols 2l,2l+1
  float iv = inv_den[(size_t)node * 4 + h];
  float al = aloop[(size_t)node * 4 + h];
  const uint_t* xu = (const uint_t*)x_l_h;   // 64 uints per row
  const int* reci = (const int*)rec;
  float accx, accy;
  {
    uint_t v = xu[(size_t)node * 64 + lane];
    float2 f = __half22float2(*(const __half2*)&v);
    accx = al * f.x; accy = al * f.y;
  }
  int i = 0;
  for (; i + 4 <= dg; i += 4) {
    size_t p0 = (size_t)(off + i) * 8, p1 = p0 + 8, p2 = p0 + 16, p3 = p0 + 24;
    float a0 = rec[p0 + h], a1 = rec[p1 + h], a2 = rec[p2 + h], a3 = rec[p3 + h];
    int s0 = reci[p0 + 4], s1 = reci[p1 + 4], s2 = reci[p2 + 4], s3 = reci[p3 + 4];
    uint_t v0 = xu[(size_t)s0 * 64 + lane];
    uint_t v1 = xu[(size_t)s1 * 64 + lane];
    uint_t v2 = xu[(size_t)s2 * 64 + lane];
    uint_t v3 = xu[(size_t)s3 * 64 + lane];
    float2 f0 = __half22float2(*(const __half2*)&v0);
    float2 f1 = __half22float2(*(const __half2*)&v1);
    float2 f2 = __half22float2(*(const __half2*)&v2);
    float2 f3 = __half22float2(*(const __half2*)&v3);
    a0 *= iv; a1 *= iv; a2 *= iv; a3 *= iv;
    accx += a0 * f0.x; accy += a0 * f0.y;
    accx += a1 * f1.x; accy += a1 * f1.y;
    accx += a2 * f2.x; accy += a2 * f2.y;
    accx += a3 * f3.x; accy += a3 * f3.y;
  }
  for (; i < dg; ++i) {
    size_t p = (size_t)(off + i) * 8;
    float a = rec[p + h] * iv;
    int s = reci[p + 4];
    uint_t v = xu[(size_t)s * 64 + lane];
    float2 f = __half22float2(*(const __half2*)&v);
    accx += a * f.x; accy += a * f.y;
  }
  float2 b2 = *(const float2*)&bias[2 * lane];
  float2 o; o.x = accx + b2.x; o.y = accy + b2.y;
  *(float2*)&out[(size_t)node * 128 + 2 * lane] = o;
}

extern "C" void kernel_launch(void* const* d_in, const int* in_sizes, int n_in,
                              void* d_out, int out_size, void* d_ws, size_t ws_size,
                              hipStream_t stream) {
  const float* x        = (const float*)d_in[0];
  const int*   ei       = (const int*)  d_in[1];
  const float* eattr    = (const float*)d_in[2];
  const float* W        = (const float*)d_in[3];
  const float* W_edge   = (const float*)d_in[4];
  const float* att_src  = (const float*)d_in[5];
  const float* att_dst  = (const float*)d_in[6];
  const float* att_edge = (const float*)d_in[7];
  const float* bias     = (const float*)d_in[8];
  float* out = (float*)d_out;
  const int N = in_sizes[0] / 128;
  const int E = in_sizes[1] / 2;
  (void)n_in; (void)out_size; (void)ws_size;

  // workspace layout (~82 MB total)
  char* base = (char*)d_ws;
  size_t off = 0;
  auto take = [&](size_t bytes) -> void* {
    void* p = base + off;
    off = (off + bytes + 255) & ~(size_t)255;
    return p;
  };
  ushort_t* x_l_h  = (ushort_t*)take((size_t)N * 128 * 2);
  float* a_src    = (float*)take((size_t)N * 4 * 4);
  float* a_dst    = (float*)take((size_t)N * 4 * 4);
  float* v_edge   = (float*)take(64 * 4);
  float* rec      = (float*)take((size_t)E * 32);      // {ae4 -> p4, src} per edge
  float* inv_den  = (float*)take((size_t)N * 4 * 4);
  float* aloop    = (float*)take((size_t)N * 4 * 4);
  int*   deg      = (int*)take((size_t)N * 4);
  int*   offs     = (int*)take((size_t)N * 4);
  int*   cursor   = (int*)take((size_t)N * 4);
  int*   bsum     = (int*)take(256 * 4);
  int*   boff     = (int*)take(256 * 4);
  int*   is64     = (int*)take(4);

  const int NB = (N + 1023) / 1024;   // 98 for N=100000 (scan2 supports <=256)

  hipLaunchKernelGGL(k_detect, dim3(1), dim3(256), 0, stream, ei, is64);
  hipLaunchKernelGGL(k_zero, dim3((N + 255) / 256), dim3(256), 0, stream, deg, N);
  hipLaunchKernelGGL(k0_vedge, dim3(1), dim3(64), 0, stream, W_edge, att_edge, v_edge);
  hipLaunchKernelGGL(k1_xl, dim3((N + 63) / 64), dim3(256), 0, stream,
                     x, W, att_src, att_dst, x_l_h, a_src, a_dst, N);
  hipLaunchKernelGGL(k_hist, dim3((E + 255) / 256), dim3(256), 0, stream, ei, is64, deg, E);
  hipLaunchKernelGGL(k_scan1, dim3(NB), dim3(256), 0, stream, deg, bsum, N);
  hipLaunchKernelGGL(k_scan2, dim3(1), dim3(256), 0, stream, bsum, boff, NB);
  hipLaunchKernelGGL(k_scan3, dim3(NB), dim3(256), 0, stream, deg, boff, offs, cursor, N);
  hipLaunchKernelGGL(k_scatter, dim3((E + 255) / 256), dim3(256), 0, stream,
                     ei, is64, eattr, v_edge, cursor, rec, E);
  hipLaunchKernelGGL(k3_softmax, dim3((N + 15) / 16), dim3(256), 0, stream,
                     rec, a_src, a_dst, deg, offs, inv_den, aloop, N);
  hipLaunchKernelGGL(k4_agg, dim3((N + 3) / 4), dim3(256), 0, stream,
                     rec, x_l_h, inv_den, aloop, deg, offs, bias, out, N);
}

// Round 3
// 300.718 us; speedup vs baseline: 1.5656x; 1.1081x over previous
//
#include <hip/hip_runtime.h>
#include <hip/hip_fp16.h>
#include <math.h>

#define NEG_SLOPE 0.2f
typedef unsigned short ushort_t;
typedef unsigned int uint_t;

// ---------------- K_prep: fused {int64-detect | v_edge | zero deg}
// block 0: detect; block 1: v_edge; blocks 2..: zero deg
__global__ void k_prep(const int* __restrict__ ei, int* __restrict__ is64,
                       int* __restrict__ deg, int N,
                       const float* __restrict__ W_edge, const float* __restrict__ att_edge,
                       float* __restrict__ v_edge) {
  int b = blockIdx.x, t = threadIdx.x;
  if (b == 0) {
    __shared__ int any;
    if (t == 0) any = 0;
    __syncthreads();
    if (ei[2 * t + 1] != 0) atomicOr(&any, 1);
    __syncthreads();
    if (t == 0) *is64 = (any == 0) ? 1 : 0;
  } else if (b == 1) {
    if (t < 64) {
      int h = t >> 4, j = t & 15;
      float s = 0.f;
#pragma unroll
      for (int c = 0; c < 32; ++c) s += W_edge[j * 128 + h * 32 + c] * att_edge[h * 32 + c];
      v_edge[t] = s;
    }
  } else {
    int i = (b - 2) * 256 + t;
    if (i < N) deg[i] = 0;
  }
}

// ---------------- K1: x_l = x @ W (f32 compute), fp16 store + fused a_src/a_dst epilogue
__global__ __launch_bounds__(256) void k1_xl(
    const float* __restrict__ x, const float* __restrict__ W,
    const float* __restrict__ att_src, const float* __restrict__ att_dst,
    ushort_t* __restrict__ x_l_h, float* __restrict__ a_src, float* __restrict__ a_dst, int N) {
  __shared__ float Wc[32 * 128];   // 16 KB
  __shared__ float Xc[32 * 64];    // 8 KB (transposed: Xc[k][r])
  const int t = threadIdx.x;
  const int tcol = t & 31;         // cols tcol*4 .. +3   (head h = tcol>>3)
  const int trow = t >> 5;         // rows trow*8 .. +7
  const int row0 = blockIdx.x * 64;
  const int r = t & 63, kq = t >> 6;
  const float4 aw_s = *(const float4*)&att_src[tcol * 4];
  const float4 aw_d = *(const float4*)&att_dst[tcol * 4];
  float acc[8][4];
#pragma unroll
  for (int i = 0; i < 8; ++i) { acc[i][0] = acc[i][1] = acc[i][2] = acc[i][3] = 0.f; }

  for (int kc = 0; kc < 4; ++kc) {
    float4 wreg[4];
#pragma unroll
    for (int q = 0; q < 4; ++q) wreg[q] = *(const float4*)&W[kc * 4096 + (q * 256 + t) * 4];
    float xs8[8];
    int grow = row0 + r;
    if (grow < N) {
      *(float4*)&xs8[0] = *(const float4*)&x[grow * 128 + kc * 32 + kq * 8];
      *(float4*)&xs8[4] = *(const float4*)&x[grow * 128 + kc * 32 + kq * 8 + 4];
    } else {
#pragma unroll
      for (int q = 0; q < 8; ++q) xs8[q] = 0.f;
    }
    __syncthreads();   // previous chunk's compute done
#pragma unroll
    for (int q = 0; q < 4; ++q) *(float4*)&Wc[(q * 256 + t) * 4] = wreg[q];
#pragma unroll
    for (int q = 0; q < 8; ++q) Xc[(kq * 8 + q) * 64 + r] = xs8[q];
    __syncthreads();
#pragma unroll
    for (int kk = 0; kk < 32; ++kk) {
      float4 wv = *(const float4*)&Wc[kk * 128 + tcol * 4];
      float xr[8];
      *(float4*)&xr[0] = *(const float4*)&Xc[kk * 64 + trow * 8];
      *(float4*)&xr[4] = *(const float4*)&Xc[kk * 64 + trow * 8 + 4];
#pragma unroll
      for (int ri = 0; ri < 8; ++ri) {
        acc[ri][0] += xr[ri] * wv.x;
        acc[ri][1] += xr[ri] * wv.y;
        acc[ri][2] += xr[ri] * wv.z;
        acc[ri][3] += xr[ri] * wv.w;
      }
    }
  }
  // epilogue: fp16 store; reduce a_src/a_dst over each head's 32 cols
#pragma unroll
  for (int ri = 0; ri < 8; ++ri) {
    int grow = row0 + trow * 8 + ri;
    float asp = acc[ri][0] * aw_s.x + acc[ri][1] * aw_s.y + acc[ri][2] * aw_s.z + acc[ri][3] * aw_s.w;
    float adp = acc[ri][0] * aw_d.x + acc[ri][1] * aw_d.y + acc[ri][2] * aw_d.z + acc[ri][3] * aw_d.w;
#pragma unroll
    for (int m = 1; m < 8; m <<= 1) { asp += __shfl_xor(asp, m); adp += __shfl_xor(adp, m); }
    if (grow < N) {
      __half2 h0 = __floats2half2_rn(acc[ri][0], acc[ri][1]);
      __half2 h1 = __floats2half2_rn(acc[ri][2], acc[ri][3]);
      uint2 u; u.x = *(uint_t*)&h0; u.y = *(uint_t*)&h1;
      *(uint2*)&x_l_h[(size_t)grow * 128 + tcol * 4] = u;
      if ((tcol & 7) == 0) {
        a_src[grow * 4 + (tcol >> 3)] = asp;
        a_dst[grow * 4 + (tcol >> 3)] = adp;
      }
    }
  }
}

// ---------------- K2a: in-degree histogram + per-edge rank (atomic return value)
__global__ void k_hist(const int* __restrict__ ei, const int* __restrict__ is64,
                       int* __restrict__ deg, int* __restrict__ rank, int E) {
  int i = blockIdx.x * blockDim.x + threadIdx.x;
  if (i >= E) return;
  int dst = (*is64) ? ei[2 * (E + i)] : ei[E + i];
  rank[i] = atomicAdd(&deg[dst], 1);
}

// ---------------- 3-kernel exclusive scan over deg[N] (1024 elems/block)
__global__ void k_scan1(const int* __restrict__ deg, int* __restrict__ bsum, int N) {
  __shared__ int lds[256];
  int b = blockIdx.x, t = threadIdx.x;
  int base = b * 1024 + t * 4;
  int s = 0;
  if (base + 3 < N) {
    int4 v = *(const int4*)&deg[base];
    s = v.x + v.y + v.z + v.w;
  } else {
    for (int q = 0; q < 4; ++q) if (base + q < N) s += deg[base + q];
  }
  lds[t] = s; __syncthreads();
  for (int st = 128; st > 0; st >>= 1) {
    if (t < st) lds[t] += lds[t + st];
    __syncthreads();
  }
  if (t == 0) bsum[b] = lds[0];
}

__global__ void k_scan2(const int* __restrict__ bsum, int* __restrict__ boff, int NB) {
  __shared__ int lds[256];
  int t = threadIdx.x;
  int v = (t < NB) ? bsum[t] : 0;
  lds[t] = v;
  __syncthreads();
  for (int st = 1; st < 256; st <<= 1) {
    int add = (t >= st) ? lds[t - st] : 0;
    __syncthreads();
    lds[t] += add;
    __syncthreads();
  }
  if (t < NB) boff[t] = lds[t] - v;   // exclusive
}

__global__ void k_scan3(const int* __restrict__ deg, const int* __restrict__ boff,
                        int* __restrict__ offs, int N) {
  __shared__ int lds[256];
  int b = blockIdx.x, t = threadIdx.x;
  int base = b * 1024 + t * 4;
  int v[4]; int s = 0;
#pragma unroll
  for (int q = 0; q < 4; ++q) { v[q] = (base + q < N) ? deg[base + q] : 0; s += v[q]; }
  lds[t] = s;
  __syncthreads();
  for (int st = 1; st < 256; st <<= 1) {
    int add = (t >= st) ? lds[t - st] : 0;
    __syncthreads();
    lds[t] += add;
    __syncthreads();
  }
  int run = boff[b] + lds[t] - s;
#pragma unroll
  for (int q = 0; q < 4; ++q) {
    if (base + q < N) offs[base + q] = run;
    run += v[q];
  }
}

// ---------------- K2c: atomic-free scatter. Coalesced edge_attr read, a_edge dot,
// ONE 16B record {half2 ae01, half2 ae23, src, pad} at dst-sorted position.
__global__ __launch_bounds__(256) void k_scatter(
    const int* __restrict__ ei, const int* __restrict__ is64,
    const int* __restrict__ rank, const int* __restrict__ offs,
    const float* __restrict__ edge_attr, const float* __restrict__ v_edge,
    int4* __restrict__ rec, int E) {
  __shared__ float ve[64];
  int t = threadIdx.x;
  if (t < 64) ve[t] = v_edge[t];
  __syncthreads();
  int i = blockIdx.x * 256 + t;
  if (i >= E) return;
  int f = *is64;
  int src = f ? ei[2 * i] : ei[i];
  int dst = f ? ei[2 * (E + i)] : ei[E + i];
  float a16[16];
  *(float4*)&a16[0]  = *(const float4*)&edge_attr[(size_t)i * 16];
  *(float4*)&a16[4]  = *(const float4*)&edge_attr[(size_t)i * 16 + 4];
  *(float4*)&a16[8]  = *(const float4*)&edge_attr[(size_t)i * 16 + 8];
  *(float4*)&a16[12] = *(const float4*)&edge_attr[(size_t)i * 16 + 12];
  float ae[4];
#pragma unroll
  for (int h = 0; h < 4; ++h) {
    float s = 0.f;
#pragma unroll
    for (int j = 0; j < 16; ++j) s += a16[j] * ve[h * 16 + j];
    ae[h] = s;
  }
  int pos = offs[dst] + rank[i];
  __half2 e01 = __floats2half2_rn(ae[0], ae[1]);
  __half2 e23 = __floats2half2_rn(ae[2], ae[3]);
  int4 r; r.x = *(int*)&e01; r.y = *(int*)&e23; r.z = src; r.w = 0;
  rec[pos] = r;
}

// ---------------- K3: per-node softmax denominators; rewrites ae->p (8B) in place.
__global__ __launch_bounds__(256) void k3_softmax(
    int4* __restrict__ rec, const float* __restrict__ a_src,
    const float* __restrict__ a_dst, const int* __restrict__ deg,
    const int* __restrict__ offs, float* __restrict__ inv_den,
    float* __restrict__ aloop, int N) {
  int t = threadIdx.x;
  int node = blockIdx.x * 16 + (t >> 4);
  int sl = t & 15;
  if (node >= N) return;
  int off = offs[node], dg = deg[node];
  float ad4[4]; *(float4*)ad4 = *(const float4*)&a_dst[(size_t)node * 4];
  uint2* rec8 = (uint2*)rec;
  float den[4] = {0, 0, 0, 0}, sae[4] = {0, 0, 0, 0};
  for (int i = sl; i < dg; i += 16) {
    int pos = off + i;
    int4 u = rec[pos];
    float2 e01 = __half22float2(*(const __half2*)&u.x);
    float2 e23 = __half22float2(*(const __half2*)&u.y);
    float aev[4] = {e01.x, e01.y, e23.x, e23.y};
    int src = u.z;
    float as4[4]; *(float4*)as4 = *(const float4*)&a_src[(size_t)src * 4];
    float p4[4];
#pragma unroll
    for (int h = 0; h < 4; ++h) {
      float lg = as4[h] + ad4[h] + aev[h];
      lg = (lg >= 0.f) ? lg : NEG_SLOPE * lg;
      float pv = __expf(lg);
      p4[h] = pv;
      den[h] += pv;
      sae[h] += aev[h];
    }
    __half2 p01 = __floats2half2_rn(p4[0], p4[1]);
    __half2 p23 = __floats2half2_rn(p4[2], p4[3]);
    uint2 w; w.x = *(uint_t*)&p01; w.y = *(uint_t*)&p23;
    rec8[(size_t)pos * 2] = w;   // overwrite ae-halves with p-halves; src intact
  }
#pragma unroll
  for (int m = 1; m < 16; m <<= 1) {
#pragma unroll
    for (int h = 0; h < 4; ++h) { den[h] += __shfl_xor(den[h], m); sae[h] += __shfl_xor(sae[h], m); }
  }
  if (sl == 0) {
    float as4[4]; *(float4*)as4 = *(const float4*)&a_src[(size_t)node * 4];
    float inv_cnt = 1.f / (float)(dg > 0 ? dg : 1);
    float id4[4], al4[4];
#pragma unroll
    for (int h = 0; h < 4; ++h) {
      float lae = sae[h] * inv_cnt;                 // mean a_edge (linearity of fill='mean')
      float lg = as4[h] + ad4[h] + lae;
      lg = (lg >= 0.f) ? lg : NEG_SLOPE * lg;
      float pl = __expf(lg);
      float dt = den[h] + pl;
      float iv = 1.f / dt;
      id4[h] = iv; al4[h] = pl * iv;
    }
    *(float4*)&inv_den[(size_t)node * 4] = *(float4*)id4;
    *(float4*)&aloop[(size_t)node * 4]  = *(float4*)al4;
  }
}

// ---------------- K4: atomic-free aggregation, one wave per node.
// Lane covers cols {2l, 2l+1} via one half2 -> ONE 256B row load per edge.
__global__ __launch_bounds__(256) void k4_agg(
    const int4* __restrict__ rec, const ushort_t* __restrict__ x_l_h,
    const float* __restrict__ inv_den, const float* __restrict__ aloop,
    const int* __restrict__ deg, const int* __restrict__ offs,
    const float* __restrict__ bias, float* __restrict__ out, int N) {
  int lane = threadIdx.x & 63;
  int node = blockIdx.x * 4 + (threadIdx.x >> 6);
  if (node >= N) return;
  int off = offs[node], dg = deg[node];
  int h = lane >> 4;                         // head of cols 2l,2l+1
  float iv = inv_den[(size_t)node * 4 + h];
  float al = aloop[(size_t)node * 4 + h];
  const uint_t* xu = (const uint_t*)x_l_h;   // 64 uints per row
  float accx, accy;
  {
    uint_t v = xu[(size_t)node * 64 + lane];
    float2 f = __half22float2(*(const __half2*)&v);
    accx = al * f.x; accy = al * f.y;
  }
  int i = 0;
  for (; i + 4 <= dg; i += 4) {
    int4 u0 = rec[off + i], u1 = rec[off + i + 1], u2 = rec[off + i + 2], u3 = rec[off + i + 3];
    uint_t w0 = (h & 2) ? (uint_t)u0.y : (uint_t)u0.x;
    uint_t w1 = (h & 2) ? (uint_t)u1.y : (uint_t)u1.x;
    uint_t w2 = (h & 2) ? (uint_t)u2.y : (uint_t)u2.x;
    uint_t w3 = (h & 2) ? (uint_t)u3.y : (uint_t)u3.x;
    float2 q0 = __half22float2(*(const __half2*)&w0);
    float2 q1 = __half22float2(*(const __half2*)&w1);
    float2 q2 = __half22float2(*(const __half2*)&w2);
    float2 q3 = __half22float2(*(const __half2*)&w3);
    float a0 = ((h & 1) ? q0.y : q0.x) * iv;
    float a1 = ((h & 1) ? q1.y : q1.x) * iv;
    float a2 = ((h & 1) ? q2.y : q2.x) * iv;
    float a3 = ((h & 1) ? q3.y : q3.x) * iv;
    uint_t v0 = xu[(size_t)u0.z * 64 + lane];
    uint_t v1 = xu[(size_t)u1.z * 64 + lane];
    uint_t v2 = xu[(size_t)u2.z * 64 + lane];
    uint_t v3 = xu[(size_t)u3.z * 64 + lane];
    float2 f0 = __half22float2(*(const __half2*)&v0);
    float2 f1 = __half22float2(*(const __half2*)&v1);
    float2 f2 = __half22float2(*(const __half2*)&v2);
    float2 f3 = __half22float2(*(const __half2*)&v3);
    accx += a0 * f0.x; accy += a0 * f0.y;
    accx += a1 * f1.x; accy += a1 * f1.y;
    accx += a2 * f2.x; accy += a2 * f2.y;
    accx += a3 * f3.x; accy += a3 * f3.y;
  }
  for (; i < dg; ++i) {
    int4 u = rec[off + i];
    uint_t w = (h & 2) ? (uint_t)u.y : (uint_t)u.x;
    float2 q = __half22float2(*(const __half2*)&w);
    float a = ((h & 1) ? q.y : q.x) * iv;
    uint_t v = xu[(size_t)u.z * 64 + lane];
    float2 f = __half22float2(*(const __half2*)&v);
    accx += a * f.x; accy += a * f.y;
  }
  float2 b2 = *(const float2*)&bias[2 * lane];
  float2 o; o.x = accx + b2.x; o.y = accy + b2.y;
  *(float2*)&out[(size_t)node * 128 + 2 * lane] = o;
}

extern "C" void kernel_launch(void* const* d_in, const int* in_sizes, int n_in,
                              void* d_out, int out_size, void* d_ws, size_t ws_size,
                              hipStream_t stream) {
  const float* x        = (const float*)d_in[0];
  const int*   ei       = (const int*)  d_in[1];
  const float* eattr    = (const float*)d_in[2];
  const float* W        = (const float*)d_in[3];
  const float* W_edge   = (const float*)d_in[4];
  const float* att_src  = (const float*)d_in[5];
  const float* att_dst  = (const float*)d_in[6];
  const float* att_edge = (const float*)d_in[7];
  const float* bias     = (const float*)d_in[8];
  float* out = (float*)d_out;
  const int N = in_sizes[0] / 128;
  const int E = in_sizes[1] / 2;
  (void)n_in; (void)out_size; (void)ws_size;

  // workspace layout (~60 MB total)
  char* base = (char*)d_ws;
  size_t off = 0;
  auto take = [&](size_t bytes) -> void* {
    void* p = base + off;
    off = (off + bytes + 255) & ~(size_t)255;
    return p;
  };
  ushort_t* x_l_h = (ushort_t*)take((size_t)N * 128 * 2);
  float* a_src    = (float*)take((size_t)N * 4 * 4);
  float* a_dst    = (float*)take((size_t)N * 4 * 4);
  float* v_edge   = (float*)take(64 * 4);
  int4*  rec      = (int4*)take((size_t)E * 16);       // {ae01,ae23 -> p01,p23, src, pad}
  float* inv_den  = (float*)take((size_t)N * 4 * 4);
  float* aloop    = (float*)take((size_t)N * 4 * 4);
  int*   deg      = (int*)take((size_t)N * 4);
  int*   offs     = (int*)take((size_t)N * 4);
  int*   rank     = (int*)take((size_t)E * 4);
  int*   bsum     = (int*)take(256 * 4);
  int*   boff     = (int*)take(256 * 4);
  int*   is64     = (int*)take(4);

  const int NB = (N + 1023) / 1024;   // 98 for N=100000 (scan2 supports <=256)

  hipLaunchKernelGGL(k_prep, dim3(2 + (N + 255) / 256), dim3(256), 0, stream,
                     ei, is64, deg, N, W_edge, att_edge, v_edge);
  hipLaunchKernelGGL(k1_xl, dim3((N + 63) / 64), dim3(256), 0, stream,
                     x, W, att_src, att_dst, x_l_h, a_src, a_dst, N);
  hipLaunchKernelGGL(k_hist, dim3((E + 255) / 256), dim3(256), 0, stream, ei, is64, deg, rank, E);
  hipLaunchKernelGGL(k_scan1, dim3(NB), dim3(256), 0, stream, deg, bsum, N);
  hipLaunchKernelGGL(k_scan2, dim3(1), dim3(256), 0, stream, bsum, boff, NB);
  hipLaunchKernelGGL(k_scan3, dim3(NB), dim3(256), 0, stream, deg, boff, offs, N);
  hipLaunchKernelGGL(k_scatter, dim3((E + 255) / 256), dim3(256), 0, stream,
                     ei, is64, rank, offs, eattr, v_edge, rec, E);
  hipLaunchKernelGGL(k3_softmax, dim3((N + 15) / 16), dim3(256), 0, stream,
                     rec, a_src, a_dst, deg, offs, inv_den, aloop, N);
  hipLaunchKernelGGL(k4_agg, dim3((N + 3) / 4), dim3(256), 0, stream,
                     rec, x_l_h, inv_den, aloop, deg, offs, bias, out, N);
}

// Round 4
// 268.640 us; speedup vs baseline: 1.7525x; 1.1194x over previous
//
#include <hip/hip_runtime.h>
#include <hip/hip_fp16.h>
#include <math.h>

#define NEG_SLOPE 0.2f
typedef unsigned short ushort_t;
typedef unsigned int uint_t;

// ---------------- K_prep: fused {int64-detect | v_edge | zero deg}
__global__ void k_prep(const int* __restrict__ ei, int* __restrict__ is64,
                       int* __restrict__ deg, int N,
                       const float* __restrict__ W_edge, const float* __restrict__ att_edge,
                       float* __restrict__ v_edge) {
  int b = blockIdx.x, t = threadIdx.x;
  if (b == 0) {
    __shared__ int any;
    if (t == 0) any = 0;
    __syncthreads();
    if (ei[2 * t + 1] != 0) atomicOr(&any, 1);
    __syncthreads();
    if (t == 0) *is64 = (any == 0) ? 1 : 0;
  } else if (b == 1) {
    if (t < 64) {
      int h = t >> 4, j = t & 15;
      float s = 0.f;
#pragma unroll
      for (int c = 0; c < 32; ++c) s += W_edge[j * 128 + h * 32 + c] * att_edge[h * 32 + c];
      v_edge[t] = s;
    }
  } else {
    int i = (b - 2) * 256 + t;
    if (i < N) deg[i] = 0;
  }
}

// ---------------- K1H: fused {x_l GEMM | degree histogram + rank}
// blocks [0, nb1): GEMM (64 rows each). blocks [nb1, nb1+nbh): histogram.
__global__ __launch_bounds__(256) void k1_hist(
    const float* __restrict__ x, const float* __restrict__ W,
    const float* __restrict__ att_src, const float* __restrict__ att_dst,
    ushort_t* __restrict__ x_l_h, float* __restrict__ a_src, float* __restrict__ a_dst, int N,
    const int* __restrict__ ei, const int* __restrict__ is64,
    int* __restrict__ deg, int* __restrict__ rank, int E, int nb1) {
  __shared__ float Wc[32 * 128];   // 16 KB
  __shared__ float Xc[32 * 64];    // 8 KB (transposed: Xc[k][r])
  if (blockIdx.x >= nb1) {
    // -------- histogram part --------
    int i = (blockIdx.x - nb1) * 256 + threadIdx.x;
    if (i < E) {
      int dst = (*is64) ? ei[2 * (E + i)] : ei[E + i];
      rank[i] = atomicAdd(&deg[dst], 1);
    }
    return;
  }
  // -------- GEMM part --------
  const int t = threadIdx.x;
  const int tcol = t & 31;         // cols tcol*4 .. +3   (head h = tcol>>3)
  const int trow = t >> 5;         // rows trow*8 .. +7
  const int row0 = blockIdx.x * 64;
  const int r = t & 63, kq = t >> 6;
  const float4 aw_s = *(const float4*)&att_src[tcol * 4];
  const float4 aw_d = *(const float4*)&att_dst[tcol * 4];
  float acc[8][4];
#pragma unroll
  for (int i = 0; i < 8; ++i) { acc[i][0] = acc[i][1] = acc[i][2] = acc[i][3] = 0.f; }

  for (int kc = 0; kc < 4; ++kc) {
    float4 wreg[4];
#pragma unroll
    for (int q = 0; q < 4; ++q) wreg[q] = *(const float4*)&W[kc * 4096 + (q * 256 + t) * 4];
    float xs8[8];
    int grow = row0 + r;
    if (grow < N) {
      *(float4*)&xs8[0] = *(const float4*)&x[grow * 128 + kc * 32 + kq * 8];
      *(float4*)&xs8[4] = *(const float4*)&x[grow * 128 + kc * 32 + kq * 8 + 4];
    } else {
#pragma unroll
      for (int q = 0; q < 8; ++q) xs8[q] = 0.f;
    }
    __syncthreads();   // previous chunk's compute done
#pragma unroll
    for (int q = 0; q < 4; ++q) *(float4*)&Wc[(q * 256 + t) * 4] = wreg[q];
#pragma unroll
    for (int q = 0; q < 8; ++q) Xc[(kq * 8 + q) * 64 + r] = xs8[q];
    __syncthreads();
#pragma unroll
    for (int kk = 0; kk < 32; ++kk) {
      float4 wv = *(const float4*)&Wc[kk * 128 + tcol * 4];
      float xr[8];
      *(float4*)&xr[0] = *(const float4*)&Xc[kk * 64 + trow * 8];
      *(float4*)&xr[4] = *(const float4*)&Xc[kk * 64 + trow * 8 + 4];
#pragma unroll
      for (int ri = 0; ri < 8; ++ri) {
        acc[ri][0] += xr[ri] * wv.x;
        acc[ri][1] += xr[ri] * wv.y;
        acc[ri][2] += xr[ri] * wv.z;
        acc[ri][3] += xr[ri] * wv.w;
      }
    }
  }
#pragma unroll
  for (int ri = 0; ri < 8; ++ri) {
    int grow = row0 + trow * 8 + ri;
    float asp = acc[ri][0] * aw_s.x + acc[ri][1] * aw_s.y + acc[ri][2] * aw_s.z + acc[ri][3] * aw_s.w;
    float adp = acc[ri][0] * aw_d.x + acc[ri][1] * aw_d.y + acc[ri][2] * aw_d.z + acc[ri][3] * aw_d.w;
#pragma unroll
    for (int m = 1; m < 8; m <<= 1) { asp += __shfl_xor(asp, m); adp += __shfl_xor(adp, m); }
    if (grow < N) {
      __half2 h0 = __floats2half2_rn(acc[ri][0], acc[ri][1]);
      __half2 h1 = __floats2half2_rn(acc[ri][2], acc[ri][3]);
      uint2 u; u.x = *(uint_t*)&h0; u.y = *(uint_t*)&h1;
      *(uint2*)&x_l_h[(size_t)grow * 128 + tcol * 4] = u;
      if ((tcol & 7) == 0) {
        a_src[grow * 4 + (tcol >> 3)] = asp;
        a_dst[grow * 4 + (tcol >> 3)] = adp;
      }
    }
  }
}

// ---------------- 3-kernel exclusive scan over deg[N] (1024 elems/block)
__global__ void k_scan1(const int* __restrict__ deg, int* __restrict__ bsum, int N) {
  __shared__ int lds[256];
  int b = blockIdx.x, t = threadIdx.x;
  int base = b * 1024 + t * 4;
  int s = 0;
  if (base + 3 < N) {
    int4 v = *(const int4*)&deg[base];
    s = v.x + v.y + v.z + v.w;
  } else {
    for (int q = 0; q < 4; ++q) if (base + q < N) s += deg[base + q];
  }
  lds[t] = s; __syncthreads();
  for (int st = 128; st > 0; st >>= 1) {
    if (t < st) lds[t] += lds[t + st];
    __syncthreads();
  }
  if (t == 0) bsum[b] = lds[0];
}

__global__ void k_scan2(const int* __restrict__ bsum, int* __restrict__ boff, int NB) {
  __shared__ int lds[256];
  int t = threadIdx.x;
  int v = (t < NB) ? bsum[t] : 0;
  lds[t] = v;
  __syncthreads();
  for (int st = 1; st < 256; st <<= 1) {
    int add = (t >= st) ? lds[t - st] : 0;
    __syncthreads();
    lds[t] += add;
    __syncthreads();
  }
  if (t < NB) boff[t] = lds[t] - v;   // exclusive
}

__global__ void k_scan3(const int* __restrict__ deg, const int* __restrict__ boff,
                        int* __restrict__ offs, int N) {
  __shared__ int lds[256];
  int b = blockIdx.x, t = threadIdx.x;
  int base = b * 1024 + t * 4;
  int v[4]; int s = 0;
#pragma unroll
  for (int q = 0; q < 4; ++q) { v[q] = (base + q < N) ? deg[base + q] : 0; s += v[q]; }
  lds[t] = s;
  __syncthreads();
  for (int st = 1; st < 256; st <<= 1) {
    int add = (t >= st) ? lds[t - st] : 0;
    __syncthreads();
    lds[t] += add;
    __syncthreads();
  }
  int run = boff[b] + lds[t] - s;
#pragma unroll
  for (int q = 0; q < 4; ++q) {
    if (base + q < N) offs[base + q] = run;
    run += v[q];
  }
}

// ---------------- K2c: atomic-free scatter. Coalesced edge_attr read, a_edge dot,
// ONE 16B record {half2 ae01, half2 ae23, src, pad} at dst-sorted position.
__global__ __launch_bounds__(256) void k_scatter(
    const int* __restrict__ ei, const int* __restrict__ is64,
    const int* __restrict__ rank, const int* __restrict__ offs,
    const float* __restrict__ edge_attr, const float* __restrict__ v_edge,
    int4* __restrict__ rec, int E) {
  __shared__ float ve[64];
  int t = threadIdx.x;
  if (t < 64) ve[t] = v_edge[t];
  __syncthreads();
  int i = blockIdx.x * 256 + t;
  if (i >= E) return;
  int f = *is64;
  int src = f ? ei[2 * i] : ei[i];
  int dst = f ? ei[2 * (E + i)] : ei[E + i];
  float a16[16];
  *(float4*)&a16[0]  = *(const float4*)&edge_attr[(size_t)i * 16];
  *(float4*)&a16[4]  = *(const float4*)&edge_attr[(size_t)i * 16 + 4];
  *(float4*)&a16[8]  = *(const float4*)&edge_attr[(size_t)i * 16 + 8];
  *(float4*)&a16[12] = *(const float4*)&edge_attr[(size_t)i * 16 + 12];
  float ae[4];
#pragma unroll
  for (int h = 0; h < 4; ++h) {
    float s = 0.f;
#pragma unroll
    for (int j = 0; j < 16; ++j) s += a16[j] * ve[h * 16 + j];
    ae[h] = s;
  }
  int pos = offs[dst] + rank[i];
  __half2 e01 = __floats2half2_rn(ae[0], ae[1]);
  __half2 e23 = __floats2half2_rn(ae[2], ae[3]);
  int4 r; r.x = *(int*)&e01; r.y = *(int*)&e23; r.z = src; r.w = 0;
  rec[pos] = r;
}

// ---------------- K34: fused softmax + aggregation, one wave per node.
// Normalization commutes with accumulation: out = (sum p*x + pl*x_node)/(sum p + pl).
// Lane covers cols {2l, 2l+1}; h = lane>>4. den/sae lane-uniform within head group.
__global__ __launch_bounds__(256) void k34_agg(
    const int4* __restrict__ rec, const ushort_t* __restrict__ x_l_h,
    const float* __restrict__ a_src, const float* __restrict__ a_dst,
    const int* __restrict__ deg, const int* __restrict__ offs,
    const float* __restrict__ bias, float* __restrict__ out, int N) {
  int lane = threadIdx.x & 63;
  int node = blockIdx.x * 4 + (threadIdx.x >> 6);
  if (node >= N) return;
  int off = offs[node], dg = deg[node];
  int h = lane >> 4;
  float ad = a_dst[(size_t)node * 4 + h];
  const uint_t* xu = (const uint_t*)x_l_h;   // 64 uints per row
  float accx = 0.f, accy = 0.f, den = 0.f, sae = 0.f;
  int i = 0;
  for (; i + 4 <= dg; i += 4) {
    int4 u0 = rec[off + i], u1 = rec[off + i + 1], u2 = rec[off + i + 2], u3 = rec[off + i + 3];
    uint_t v0 = xu[(size_t)u0.z * 64 + lane];
    uint_t v1 = xu[(size_t)u1.z * 64 + lane];
    uint_t v2 = xu[(size_t)u2.z * 64 + lane];
    uint_t v3 = xu[(size_t)u3.z * 64 + lane];
    float s0 = a_src[(size_t)u0.z * 4 + h];
    float s1 = a_src[(size_t)u1.z * 4 + h];
    float s2 = a_src[(size_t)u2.z * 4 + h];
    float s3 = a_src[(size_t)u3.z * 4 + h];
    uint_t w0 = (h & 2) ? (uint_t)u0.y : (uint_t)u0.x;
    uint_t w1 = (h & 2) ? (uint_t)u1.y : (uint_t)u1.x;
    uint_t w2 = (h & 2) ? (uint_t)u2.y : (uint_t)u2.x;
    uint_t w3 = (h & 2) ? (uint_t)u3.y : (uint_t)u3.x;
    float2 q0 = __half22float2(*(const __half2*)&w0);
    float2 q1 = __half22float2(*(const __half2*)&w1);
    float2 q2 = __half22float2(*(const __half2*)&w2);
    float2 q3 = __half22float2(*(const __half2*)&w3);
    float e0 = (h & 1) ? q0.y : q0.x;
    float e1 = (h & 1) ? q1.y : q1.x;
    float e2 = (h & 1) ? q2.y : q2.x;
    float e3 = (h & 1) ? q3.y : q3.x;
    float g0 = s0 + ad + e0; g0 = (g0 >= 0.f) ? g0 : NEG_SLOPE * g0;
    float g1 = s1 + ad + e1; g1 = (g1 >= 0.f) ? g1 : NEG_SLOPE * g1;
    float g2 = s2 + ad + e2; g2 = (g2 >= 0.f) ? g2 : NEG_SLOPE * g2;
    float g3 = s3 + ad + e3; g3 = (g3 >= 0.f) ? g3 : NEG_SLOPE * g3;
    float p0 = __expf(g0), p1 = __expf(g1), p2 = __expf(g2), p3 = __expf(g3);
    den += p0 + p1 + p2 + p3;
    sae += e0 + e1 + e2 + e3;
    float2 f0 = __half22float2(*(const __half2*)&v0);
    float2 f1 = __half22float2(*(const __half2*)&v1);
    float2 f2 = __half22float2(*(const __half2*)&v2);
    float2 f3 = __half22float2(*(const __half2*)&v3);
    accx += p0 * f0.x; accy += p0 * f0.y;
    accx += p1 * f1.x; accy += p1 * f1.y;
    accx += p2 * f2.x; accy += p2 * f2.y;
    accx += p3 * f3.x; accy += p3 * f3.y;
  }
  for (; i < dg; ++i) {
    int4 u = rec[off + i];
    uint_t v = xu[(size_t)u.z * 64 + lane];
    float as = a_src[(size_t)u.z * 4 + h];
    uint_t w = (h & 2) ? (uint_t)u.y : (uint_t)u.x;
    float2 q = __half22float2(*(const __half2*)&w);
    float ae = (h & 1) ? q.y : q.x;
    float g = as + ad + ae; g = (g >= 0.f) ? g : NEG_SLOPE * g;
    float p = __expf(g);
    den += p; sae += ae;
    float2 f = __half22float2(*(const __half2*)&v);
    accx += p * f.x; accy += p * f.y;
  }
  // self loop (edge_attr = mean of incoming => a_edge_loop = mean(ae), linearity)
  float as_n = a_src[(size_t)node * 4 + h];
  float inv_cnt = 1.f / (float)(dg > 0 ? dg : 1);
  float gl = as_n + ad + sae * inv_cnt;
  gl = (gl >= 0.f) ? gl : NEG_SLOPE * gl;
  float pl = __expf(gl);
  float iv = 1.f / (den + pl);
  uint_t vn = xu[(size_t)node * 64 + lane];
  float2 fn = __half22float2(*(const __half2*)&vn);
  float2 b2 = *(const float2*)&bias[2 * lane];
  float2 o;
  o.x = (accx + pl * fn.x) * iv + b2.x;
  o.y = (accy + pl * fn.y) * iv + b2.y;
  *(float2*)&out[(size_t)node * 128 + 2 * lane] = o;
}

extern "C" void kernel_launch(void* const* d_in, const int* in_sizes, int n_in,
                              void* d_out, int out_size, void* d_ws, size_t ws_size,
                              hipStream_t stream) {
  const float* x        = (const float*)d_in[0];
  const int*   ei       = (const int*)  d_in[1];
  const float* eattr    = (const float*)d_in[2];
  const float* W        = (const float*)d_in[3];
  const float* W_edge   = (const float*)d_in[4];
  const float* att_src  = (const float*)d_in[5];
  const float* att_dst  = (const float*)d_in[6];
  const float* att_edge = (const float*)d_in[7];
  const float* bias     = (const float*)d_in[8];
  float* out = (float*)d_out;
  const int N = in_sizes[0] / 128;
  const int E = in_sizes[1] / 2;
  (void)n_in; (void)out_size; (void)ws_size;

  char* base = (char*)d_ws;
  size_t off = 0;
  auto take = [&](size_t bytes) -> void* {
    void* p = base + off;
    off = (off + bytes + 255) & ~(size_t)255;
    return p;
  };
  ushort_t* x_l_h = (ushort_t*)take((size_t)N * 128 * 2);
  float* a_src    = (float*)take((size_t)N * 4 * 4);
  float* a_dst    = (float*)take((size_t)N * 4 * 4);
  float* v_edge   = (float*)take(64 * 4);
  int4*  rec      = (int4*)take((size_t)E * 16);       // {ae01, ae23, src, pad}
  int*   deg      = (int*)take((size_t)N * 4);
  int*   offs     = (int*)take((size_t)N * 4);
  int*   rank     = (int*)take((size_t)E * 4);
  int*   bsum     = (int*)take(256 * 4);
  int*   boff     = (int*)take(256 * 4);
  int*   is64     = (int*)take(4);

  const int NB = (N + 1023) / 1024;   // 98 for N=100000 (scan2 supports <=256)
  const int nb1 = (N + 63) / 64;      // GEMM blocks
  const int nbh = (E + 255) / 256;    // histogram blocks

  hipLaunchKernelGGL(k_prep, dim3(2 + (N + 255) / 256), dim3(256), 0, stream,
                     ei, is64, deg, N, W_edge, att_edge, v_edge);
  hipLaunchKernelGGL(k1_hist, dim3(nb1 + nbh), dim3(256), 0, stream,
                     x, W, att_src, att_dst, x_l_h, a_src, a_dst, N,
                     ei, is64, deg, rank, E, nb1);
  hipLaunchKernelGGL(k_scan1, dim3(NB), dim3(256), 0, stream, deg, bsum, N);
  hipLaunchKernelGGL(k_scan2, dim3(1), dim3(256), 0, stream, bsum, boff, NB);
  hipLaunchKernelGGL(k_scan3, dim3(NB), dim3(256), 0, stream, deg, boff, offs, N);
  hipLaunchKernelGGL(k_scatter, dim3(nbh), dim3(256), 0, stream,
                     ei, is64, rank, offs, eattr, v_edge, rec, E);
  hipLaunchKernelGGL(k34_agg, dim3((N + 3) / 4), dim3(256), 0, stream,
                     rec, x_l_h, a_src, a_dst, deg, offs, bias, out, N);
}